// Round 8
// baseline (482.153 us; speedup 1.0000x reference)
//
#include <hip/hip_runtime.h>
#include <hip/hip_bf16.h>

typedef unsigned short u16;
typedef unsigned int u32;
typedef short bf16x8 __attribute__((ext_vector_type(8)));
typedef float f32x4 __attribute__((ext_vector_type(4)));

__device__ __forceinline__ u16 f2bf(float x) {
    u32 u = __float_as_uint(x);
    u32 rounding = 0x7FFFu + ((u >> 16) & 1u);
    return (u16)((u + rounding) >> 16);
}

// async global->LDS, 16B per lane; lds base must be wave-uniform + lane*16.
__device__ __forceinline__ void gload_lds16(const u16* g, u16* l) {
    __builtin_amdgcn_global_load_lds((const __attribute__((address_space(1))) void*)g,
                                     (__attribute__((address_space(3))) void*)l, 16, 0, 0);
}

// bijective XCD-chunked block remap (m204 form)
__device__ __forceinline__ int xcd_swz(int id, int nwg) {
    int q = nwg >> 3, r = nwg & 7;
    int x = id & 7, k = id >> 3;
    return (x < r ? x * (q + 1) : r * (q + 1) + (x - r) * q) + k;
}

// ---------------- LayerNorm (fp32 in -> bf16 out) ----------------
__global__ __launch_bounds__(256) void ln_kernel(const float* __restrict__ in,
                                                 const float* __restrict__ g,
                                                 const float* __restrict__ b,
                                                 u16* __restrict__ outp) {
    int tok = blockIdx.x;
    int t = threadIdx.x;
    const float4* row = (const float4*)(in + (size_t)tok * 1024);
    float4 v = row[t];
    float s = v.x + v.y + v.z + v.w;
    float sq = v.x * v.x + v.y * v.y + v.z * v.z + v.w * v.w;
#pragma unroll
    for (int off = 32; off >= 1; off >>= 1) {
        s += __shfl_xor(s, off);
        sq += __shfl_xor(sq, off);
    }
    __shared__ float rs[4], rq[4];
    int lane = t & 63, w = t >> 6;
    if (lane == 0) { rs[w] = s; rq[w] = sq; }
    __syncthreads();
    s = rs[0] + rs[1] + rs[2] + rs[3];
    sq = rq[0] + rq[1] + rq[2] + rq[3];
    float mean = s * (1.0f / 1024.0f);
    float var = sq * (1.0f / 1024.0f) - mean * mean;
    float rstd = rsqrtf(var + 1e-5f);
    float4 gg = ((const float4*)g)[t];
    float4 bb = ((const float4*)b)[t];
    u16* o = outp + (size_t)tok * 1024 + t * 4;
    o[0] = f2bf((v.x - mean) * rstd * gg.x + bb.x);
    o[1] = f2bf((v.y - mean) * rstd * gg.y + bb.y);
    o[2] = f2bf((v.z - mean) * rstd * gg.z + bb.z);
    o[3] = f2bf((v.w - mean) * rstd * gg.w + bb.w);
}

// ---------------- Weight transpose fp32 (K x N) -> bf16 (N x K) ----------------
__global__ __launch_bounds__(256) void transpose_w(const float* __restrict__ W,
                                                   u16* __restrict__ WT, int K, int N) {
    __shared__ float tile[32][33];
    int n0 = blockIdx.x * 32, k0 = blockIdx.y * 32;
    int tx = threadIdx.x & 31, ty = threadIdx.x >> 5;  // ty 0..7
#pragma unroll
    for (int i = 0; i < 4; i++) {
        int kk = ty + i * 8;
        tile[kk][tx] = W[(size_t)(k0 + kk) * N + n0 + tx];
    }
    __syncthreads();
#pragma unroll
    for (int i = 0; i < 4; i++) {
        int nn = ty + i * 8;
        WT[(size_t)(n0 + nn) * K + k0 + tx] = f2bf(tile[tx][nn]);
    }
}

// ---------------- fp32 -> bf16 elementwise ----------------
__global__ void convert_bf(const float* __restrict__ in, u16* __restrict__ outp, int n) {
    int i = blockIdx.x * blockDim.x + threadIdx.x;
    if (i < n) outp[i] = f2bf(in[i]);
}

// ---------------- K/V pre-tiler for attention ----------------
__global__ __launch_bounds__(256) void prep_kv(const u16* __restrict__ src,
                                               u32* __restrict__ kdst, u32* __restrict__ vdst,
                                               long bstride, int rstride, int koff, int voff) {
    int t = blockIdx.x, bh = blockIdx.y;
    int b = bh >> 4, h = bh & 15;
    int tid = threadIdx.x;
    const u16* kS = src + (size_t)b * bstride + (size_t)(t * 64) * rstride + koff + h * 64;
    const u16* vS = src + (size_t)b * bstride + (size_t)(t * 64) * rstride + voff + h * 64;
    u32* kD = kdst + ((size_t)bh * gridDim.x + t) * 2048;
    u32* vD = vdst + ((size_t)bh * gridDim.x + t) * 2048;
#pragma unroll
    for (int c = 0; c < 2; c++) {
        int idx = tid + c * 256;
        int row = idx >> 3, blk = idx & 7;
        uint4 q = *(const uint4*)&kS[(size_t)row * rstride + blk * 8];
        *(uint4*)&kD[row * 32 + ((blk ^ (row & 7)) << 2)] = q;
    }
#pragma unroll
    for (int c = 0; c < 2; c++) {
        int idx = tid + c * 256;
        int drow = idx >> 3, kblk = idx & 7;
        u32 vv[4];
#pragma unroll
        for (int e = 0; e < 4; e++) {
            int j0 = kblk * 8 + 2 * e, j1 = j0 + 1;
            int kv0 = 16 * (j0 & 3) + (j0 >> 2);
            int kv1 = 16 * (j1 & 3) + (j1 >> 2);
            vv[e] = (u32)vS[(size_t)kv0 * rstride + drow] |
                    ((u32)vS[(size_t)kv1 * rstride + drow] << 16);
        }
        *(uint4*)&vD[drow * 32 + ((kblk ^ (drow & 7)) << 2)] = *(uint4*)vv;
    }
}

// ---------------- Generic bf16 MFMA GEMM: C = A(MxK) * B^T(NxK) ----------------
// Depth-3 pipeline (T3+T4): 3 LDS buffer sets, 2 tiles of prefetch in flight,
// counted s_waitcnt vmcnt(N) (never 0 mid-loop) + raw s_barriers. Loads cross
// barriers in flight; the vmcnt(0)-drain stall of the 2-phase form is gone.
// MODE 0: out bf16 = acc + bias ; MODE 1: gelu ; MODE 2: f32 acc + bias + res
template <int MODE, int BM>
__global__ __launch_bounds__(256) void gemm_bf16(const u16* A, const u16* BT,
                                                 const float* __restrict__ bias,
                                                 const float* res, void* outv,
                                                 int M, int N, int K) {
    __shared__ __align__(16) u16 As[3][BM * 32];
    __shared__ __align__(16) u16 Bs[3][128 * 32];
    constexpr int MI = BM / 32;
    int gx = gridDim.x, gy = gridDim.y;
    int id = blockIdx.y * gx + blockIdx.x;
    int id2 = xcd_swz(id, gx * gy);
    int bx = id2 / gy, by = id2 % gy;  // column-major: each XCD chunk = few B-panels
    int rowBase = by * BM, colBase = bx * 128;
    int t = threadIdx.x, lane = t & 63, w = t >> 6;
    int wr = w >> 1, wc = w & 1, r = lane & 15, g = lane >> 4;

    int lrow = lane >> 2;
    int scol = (lane & 3) * 8;
    const u16* b0 = BT + (size_t)(colBase + (w * 2 + 0) * 16 + lrow) * K + scol;
    const u16* b1 = BT + (size_t)(colBase + (w * 2 + 1) * 16 + lrow) * K + scol;
    int lB0 = (w * 2 + 0) * 512;
    int lB1 = (w * 2 + 1) * 512;
    const u16* a0;
    const u16* a1 = nullptr;
    int lA0, lA1 = 0;
    if constexpr (BM == 128) {
        a0 = A + (size_t)(rowBase + (w * 2 + 0) * 16 + lrow) * K + scol;
        a1 = A + (size_t)(rowBase + (w * 2 + 1) * 16 + lrow) * K + scol;
        lA0 = (w * 2 + 0) * 512;
        lA1 = (w * 2 + 1) * 512;
    } else {
        a0 = A + (size_t)(rowBase + w * 16 + lrow) * K + scol;
        lA0 = w * 512;
    }

    auto stage = [&](int k0, u16* Ab, u16* Bb) {
        gload_lds16(a0 + k0, Ab + lA0);
        if constexpr (BM == 128) gload_lds16(a1 + k0, Ab + lA1);
        gload_lds16(b0 + k0, Bb + lB0);
        gload_lds16(b1 + k0, Bb + lB1);
    };

    u16 *pA0 = &As[0][0], *pA1 = &As[1][0], *pA2 = &As[2][0];
    u16 *pB0 = &Bs[0][0], *pB1 = &Bs[1][0], *pB2 = &Bs[2][0];

    f32x4 acc[MI][4] = {};
    int nk = K >> 5;
    stage(0, pA0, pB0);
    stage(32, pA1, pB1);
    for (int kt = 0; kt < nk; kt++) {
        if (kt + 2 < nk) {
            stage((kt + 2) << 5, pA2, pB2);
            // wait for tile kt only; tiles kt+1, kt+2 (2L loads) stay in flight
            if constexpr (BM == 128) asm volatile("s_waitcnt vmcnt(8)" ::: "memory");
            else                     asm volatile("s_waitcnt vmcnt(6)" ::: "memory");
        } else if (kt + 1 < nk) {
            if constexpr (BM == 128) asm volatile("s_waitcnt vmcnt(4)" ::: "memory");
            else                     asm volatile("s_waitcnt vmcnt(3)" ::: "memory");
        } else {
            asm volatile("s_waitcnt vmcnt(0)" ::: "memory");
        }
        __builtin_amdgcn_s_barrier();  // all waves' tile-kt loads now visible
        bf16x8 af[MI], bfr[4];
#pragma unroll
        for (int mi = 0; mi < MI; mi++)
            af[mi] = *(const bf16x8*)&pA0[(wr * (BM / 2) + mi * 16 + r) * 32 + g * 8];
#pragma unroll
        for (int ni = 0; ni < 4; ni++)
            bfr[ni] = *(const bf16x8*)&pB0[(wc * 64 + ni * 16 + r) * 32 + g * 8];
        __builtin_amdgcn_s_setprio(1);
#pragma unroll
        for (int mi = 0; mi < MI; mi++)
#pragma unroll
            for (int ni = 0; ni < 4; ni++)
                acc[mi][ni] = __builtin_amdgcn_mfma_f32_16x16x32_bf16(af[mi], bfr[ni], acc[mi][ni], 0, 0, 0);
        __builtin_amdgcn_s_setprio(0);
        __builtin_amdgcn_s_barrier();  // everyone done reading buf kt before it's re-staged
        u16* tA = pA0; pA0 = pA1; pA1 = pA2; pA2 = tA;
        u16* tB = pB0; pB0 = pB1; pB1 = pB2; pB2 = tB;
    }

#pragma unroll
    for (int mi = 0; mi < MI; mi++) {
#pragma unroll
        for (int ni = 0; ni < 4; ni++) {
#pragma unroll
            for (int rr = 0; rr < 4; rr++) {
                int grow = rowBase + wr * (BM / 2) + mi * 16 + g * 4 + rr;
                int gcol = colBase + wc * 64 + ni * 16 + r;
                if (grow < M) {
                    float v = acc[mi][ni][rr] + bias[gcol];
                    if constexpr (MODE == 1) {
                        v = 0.5f * v * (1.0f + erff(v * 0.70710678118f));
                    }
                    if constexpr (MODE == 2) {
                        ((float*)outv)[(size_t)grow * N + gcol] = v + res[(size_t)grow * N + gcol];
                    } else {
                        ((u16*)outv)[(size_t)grow * N + gcol] = f2bf(v);
                    }
                }
            }
        }
    }
}

// ---------------- Flash attention + compressive memory read ----------------
__global__ __launch_bounds__(256) void attn_kernel(const u16* __restrict__ qkv,
                                                   const u32* __restrict__ ktiled,
                                                   const u32* __restrict__ vttiled,
                                                   const u32* __restrict__ memK,
                                                   const u32* __restrict__ memVT,
                                                   u16* __restrict__ outp) {
    __shared__ __align__(16) u32 KB[2][2048];   // [64 rows][32 u32], blk^=(row&7)
    __shared__ __align__(16) u32 VB[2][2048];
    __shared__ __align__(16) u32 P32[64][32];   // blk^=(row&7)
    const int T = 2048, C3 = 3072;
    int id = blockIdx.y * 32 + blockIdx.x;
    int id2 = xcd_swz(id, 1024);
    int bh = id2 >> 5, qt = id2 & 31;
    int b = bh >> 4, h = bh & 15;
    int t0 = qt * 64;
    int tid = threadIdx.x, lane = tid & 63, w = tid >> 6, r = lane & 15, g = lane >> 4;
    int swz = r & 7;
    size_t qkvb = (size_t)b * T * C3;

    // Q fragments, pre-scaled by 1/sqrt(D) * log2(e) (S in log2 domain)
    const u16* qrow = qkv + qkvb + (size_t)(t0 + w * 16 + r) * C3 + h * 64;
    bf16x8 aq0 = *(const bf16x8*)(qrow + g * 8);
    bf16x8 aq1 = *(const bf16x8*)(qrow + 32 + g * 8);
#pragma unroll
    for (int i = 0; i < 8; i++) {
        float f0 = __uint_as_float(((u32)(u16)aq0[i]) << 16) * 0.18033688f;
        float f1 = __uint_as_float(((u32)(u16)aq1[i]) << 16) * 0.18033688f;
        aq0[i] = (short)f2bf(f0);
        aq1[i] = (short)f2bf(f1);
    }

    f32x4 O[4] = {};
    float m_[4] = {-1e30f, -1e30f, -1e30f, -1e30f};
    float lv[4] = {0.f, 0.f, 0.f, 0.f};

    auto stage = [&](int t, int buf) {
        const u32 *kb, *vb;
        if (t < 32) {
            kb = ktiled + ((size_t)bh * 32 + t) * 2048;
            vb = vttiled + ((size_t)bh * 32 + t) * 2048;
        } else {
            kb = memK + (size_t)h * 2048;
            vb = memVT + (size_t)h * 2048;
        }
        gload_lds16((const u16*)(kb + tid * 4), (u16*)&KB[buf][tid * 4]);
        gload_lds16((const u16*)(kb + 1024 + tid * 4), (u16*)&KB[buf][1024 + tid * 4]);
        gload_lds16((const u16*)(vb + tid * 4), (u16*)&VB[buf][tid * 4]);
        gload_lds16((const u16*)(vb + 1024 + tid * 4), (u16*)&VB[buf][1024 + tid * 4]);
    };

    auto compute = [&](int buf) {
        f32x4 sv[4];
#pragma unroll
        for (int n = 0; n < 4; n++) {
            int row = n * 16 + r;
            bf16x8 bk0 = *(const bf16x8*)&KB[buf][row * 32 + ((g ^ swz) << 2)];
            bf16x8 bk1 = *(const bf16x8*)&KB[buf][row * 32 + (((4 + g) ^ swz) << 2)];
            f32x4 z = {0.f, 0.f, 0.f, 0.f};
            z = __builtin_amdgcn_mfma_f32_16x16x32_bf16(aq0, bk0, z, 0, 0, 0);
            z = __builtin_amdgcn_mfma_f32_16x16x32_bf16(aq1, bk1, z, 0, 0, 0);
            sv[n] = z;
        }
        // defer-max: lane-local check, full reduce+rescale only when violated
        float mxl[4];
#pragma unroll
        for (int rr = 0; rr < 4; rr++)
            mxl[rr] = fmaxf(fmaxf(sv[0][rr], sv[1][rr]), fmaxf(sv[2][rr], sv[3][rr]));
        float dmax = fmaxf(fmaxf(mxl[0] - m_[0], mxl[1] - m_[1]),
                           fmaxf(mxl[2] - m_[2], mxl[3] - m_[3]));
        if (!__all(dmax <= 8.0f)) {
#pragma unroll
            for (int rr = 0; rr < 4; rr++) {
                float mxr = mxl[rr];
#pragma unroll
                for (int off = 8; off >= 1; off >>= 1) mxr = fmaxf(mxr, __shfl_xor(mxr, off));
                float mn = fmaxf(m_[rr], mxr);
                float alpha = exp2f(m_[rr] - mn);
                m_[rr] = mn;
                lv[rr] *= alpha;
#pragma unroll
                for (int n = 0; n < 4; n++) O[n][rr] *= alpha;
            }
        }
        // P = exp2(S - m), truncation-packed along k'
#pragma unroll
        for (int rr = 0; rr < 4; rr++) {
            int q = w * 16 + g * 4 + rr;
            float p0 = exp2f(sv[0][rr] - m_[rr]);
            float p1 = exp2f(sv[1][rr] - m_[rr]);
            float p2 = exp2f(sv[2][rr] - m_[rr]);
            float p3 = exp2f(sv[3][rr] - m_[rr]);
            lv[rr] += (p0 + p1) + (p2 + p3);
            uint2 pw;
            pw.x = __builtin_amdgcn_perm(__float_as_uint(p1), __float_as_uint(p0), 0x07060302u);
            pw.y = __builtin_amdgcn_perm(__float_as_uint(p3), __float_as_uint(p2), 0x07060302u);
            *(uint2*)&P32[q][4 * ((r >> 1) ^ (q & 7)) + 2 * (r & 1)] = pw;
        }
        // O += P V  (same-wave LDS dep; rows w*16..w*16+15 only)
        bf16x8 ap0 = *(const bf16x8*)&P32[w * 16 + r][(g ^ swz) << 2];
        bf16x8 ap1 = *(const bf16x8*)&P32[w * 16 + r][((4 + g) ^ swz) << 2];
#pragma unroll
        for (int n = 0; n < 4; n++) {
            int row = n * 16 + r;
            bf16x8 bv0 = *(const bf16x8*)&VB[buf][row * 32 + ((g ^ swz) << 2)];
            bf16x8 bv1 = *(const bf16x8*)&VB[buf][row * 32 + (((4 + g) ^ swz) << 2)];
            O[n] = __builtin_amdgcn_mfma_f32_16x16x32_bf16(ap0, bv0, O[n], 0, 0, 0);
            O[n] = __builtin_amdgcn_mfma_f32_16x16x32_bf16(ap1, bv1, O[n], 0, 0, 0);
        }
    };

    float outLocal[4][4];
    stage(0, 0);
    __syncthreads();
    for (int tt = 0; tt <= 32; tt++) {
        if (tt < 32) stage(tt + 1, (tt + 1) & 1);
        if (tt == 32) {
            // finalize local attention before the mem tile
#pragma unroll
            for (int rr = 0; rr < 4; rr++) {
                float ls = lv[rr];
#pragma unroll
                for (int off = 8; off >= 1; off >>= 1) ls += __shfl_xor(ls, off);
                float inv = 1.0f / ls;
#pragma unroll
                for (int n = 0; n < 4; n++) outLocal[n][rr] = O[n][rr] * inv;
                m_[rr] = -1e30f;
                lv[rr] = 0.f;
            }
#pragma unroll
            for (int n = 0; n < 4; n++) { f32x4 z = {0.f, 0.f, 0.f, 0.f}; O[n] = z; }
        }
        compute(tt & 1);
        __syncthreads();
    }
#pragma unroll
    for (int rr = 0; rr < 4; rr++) {
        float ls = lv[rr];
#pragma unroll
        for (int off = 8; off >= 1; off >>= 1) ls += __shfl_xor(ls, off);
        float inv = 1.0f / ls;
        int row = t0 + w * 16 + g * 4 + rr;
#pragma unroll
        for (int n = 0; n < 4; n++) {
            float v2 = outLocal[n][rr] + O[n][rr] * inv;
            outp[((size_t)(b * T + row)) * 1024 + h * 64 + n * 16 + r] = f2bf(v2);
        }
    }
}

extern "C" void kernel_launch(void* const* d_in, const int* in_sizes, int n_in,
                              void* d_out, int out_size, void* d_ws, size_t ws_size,
                              hipStream_t stream) {
    const float* x      = (const float*)d_in[0];
    const float* memory = (const float*)d_in[1];
    const float* ln1_g  = (const float*)d_in[2];
    const float* ln1_b  = (const float*)d_in[3];
    const float* w_qkv  = (const float*)d_in[4];
    const float* b_qkv  = (const float*)d_in[5];
    const float* w_out  = (const float*)d_in[6];
    const float* b_out  = (const float*)d_in[7];
    const float* w_mem  = (const float*)d_in[8];
    const float* b_mem  = (const float*)d_in[9];
    const float* ln2_g  = (const float*)d_in[10];
    const float* ln2_b  = (const float*)d_in[11];
    const float* w_fc1  = (const float*)d_in[12];
    const float* b_fc1  = (const float*)d_in[13];
    const float* w_fc2  = (const float*)d_in[14];
    const float* b_fc2  = (const float*)d_in[15];
    float* out = (float*)d_out;

    char* ws = (char*)d_ws;
    size_t off = 0;
    auto alloc = [&](size_t bytes) { size_t o = off; off += (bytes + 255) & ~(size_t)255; return o; };
    u16* h_bf    = (u16*)(ws + alloc((size_t)4096 * 1024 * 2));  // reused for h2
    u16* qkv_bf  = (u16*)(ws + alloc((size_t)4096 * 3072 * 2));
    u16* attn_bf = (u16*)(ws + alloc((size_t)4096 * 1024 * 2));
    u16* g1_bf   = (u16*)(ws + alloc((size_t)4096 * 4096 * 2));
    u16* mem_bf  = (u16*)(ws + alloc((size_t)64 * 1024 * 2));
    u16* memA_bf = (u16*)(ws + alloc((size_t)64 * 1024 * 2));
    u16* wqkvT   = (u16*)(ws + alloc((size_t)3072 * 1024 * 2));
    u16* woutT   = (u16*)(ws + alloc((size_t)1024 * 1024 * 2));
    u16* wmemT   = (u16*)(ws + alloc((size_t)1024 * 1024 * 2));
    u16* wfc1T   = (u16*)(ws + alloc((size_t)4096 * 1024 * 2));
    u16* wfc2T   = (u16*)(ws + alloc((size_t)1024 * 4096 * 2));

    // K/V pre-tiled buffers alias the g1_bf region (lifetimes disjoint: prep+attn
    // finish before fc1 writes g1_bf).
    u32* ktiled  = (u32*)g1_bf;                    // 32bh x 32t x 2048 u32 = 8 MB
    u32* vttiled = ktiled + (size_t)1024 * 2048;   // 8 MB
    u32* memK    = vttiled + (size_t)1024 * 2048;  // 16h x 2048 u32 = 128 KB
    u32* memVT   = memK + (size_t)16 * 2048;       // 128 KB

    // weights -> bf16 transposed (N x K)
    transpose_w<<<dim3(3072 / 32, 1024 / 32), 256, 0, stream>>>(w_qkv, wqkvT, 1024, 3072);
    transpose_w<<<dim3(1024 / 32, 1024 / 32), 256, 0, stream>>>(w_out, woutT, 1024, 1024);
    transpose_w<<<dim3(1024 / 32, 1024 / 32), 256, 0, stream>>>(w_mem, wmemT, 1024, 1024);
    transpose_w<<<dim3(4096 / 32, 1024 / 32), 256, 0, stream>>>(w_fc1, wfc1T, 1024, 4096);
    transpose_w<<<dim3(1024 / 32, 4096 / 32), 256, 0, stream>>>(w_fc2, wfc2T, 4096, 1024);
    convert_bf<<<dim3(256), 256, 0, stream>>>(memory, memA_bf, 64 * 1024);

    // LN1: x -> h (bf16)
    ln_kernel<<<dim3(4096), 256, 0, stream>>>(x, ln1_g, ln1_b, h_bf);

    // qkv = h @ w_qkv + b_qkv   (bf16 out)
    gemm_bf16<0, 128><<<dim3(24, 32), 256, 0, stream>>>(h_bf, wqkvT, b_qkv, nullptr, qkv_bf, 4096, 3072, 1024);

    // mem = memory @ w_mem + b_mem  (bf16 out, 64 x 1024)
    gemm_bf16<0, 64><<<dim3(8, 1), 256, 0, stream>>>(memA_bf, wmemT, b_mem, nullptr, mem_bf, 64, 1024, 1024);

    // pre-tile K and V^T (local KV from qkv; mem KV from mem_bf)
    prep_kv<<<dim3(32, 32), 256, 0, stream>>>(qkv_bf, ktiled, vttiled,
                                              (long)2048 * 3072, 3072, 1024, 2048);
    prep_kv<<<dim3(1, 16), 256, 0, stream>>>(mem_bf, memK, memVT, 0, 1024, 0, 0);

    // attention (local + memory) -> attn_bf
    attn_kernel<<<dim3(32, 32), 256, 0, stream>>>(qkv_bf, ktiled, vttiled, memK, memVT, attn_bf);

    // x1 = x + attn @ w_out + b_out   (fp32, lives in d_out)
    gemm_bf16<2, 64><<<dim3(8, 64), 256, 0, stream>>>(attn_bf, woutT, b_out, x, out, 4096, 1024, 1024);

    // LN2: x1 -> h2 (bf16, reuse h_bf)
    ln_kernel<<<dim3(4096), 256, 0, stream>>>(out, ln2_g, ln2_b, h_bf);

    // g1 = gelu(h2 @ w_fc1 + b_fc1)  (bf16)
    gemm_bf16<1, 128><<<dim3(32, 32), 256, 0, stream>>>(h_bf, wfc1T, b_fc1, nullptr, g1_bf, 4096, 4096, 1024);

    // out = x1 + g1 @ w_fc2 + b_fc2  (fp32, in-place over x1)
    gemm_bf16<2, 64><<<dim3(8, 64), 256, 0, stream>>>(g1_bf, wfc2T, b_fc2, out, out, 4096, 1024, 4096);

    (void)in_sizes; (void)n_in; (void)out_size; (void)ws_size;
}

// Round 9
// 447.220 us; speedup vs baseline: 1.0781x; 1.0781x over previous
//
#include <hip/hip_runtime.h>
#include <hip/hip_bf16.h>

typedef unsigned short u16;
typedef unsigned int u32;
typedef short bf16x8 __attribute__((ext_vector_type(8)));
typedef float f32x4 __attribute__((ext_vector_type(4)));

__device__ __forceinline__ u16 f2bf(float x) {
    u32 u = __float_as_uint(x);
    u32 rounding = 0x7FFFu + ((u >> 16) & 1u);
    return (u16)((u + rounding) >> 16);
}

// async global->LDS, 16B per lane; lds base must be wave-uniform + lane*16.
__device__ __forceinline__ void gload_lds16(const u16* g, u16* l) {
    __builtin_amdgcn_global_load_lds((const __attribute__((address_space(1))) void*)g,
                                     (__attribute__((address_space(3))) void*)l, 16, 0, 0);
}

// bijective XCD-chunked block remap (m204 form)
__device__ __forceinline__ int xcd_swz(int id, int nwg) {
    int q = nwg >> 3, r = nwg & 7;
    int x = id & 7, k = id >> 3;
    return (x < r ? x * (q + 1) : r * (q + 1) + (x - r) * q) + k;
}

// ---------------- LayerNorm (fp32 in -> bf16 out) ----------------
__global__ __launch_bounds__(256) void ln_kernel(const float* __restrict__ in,
                                                 const float* __restrict__ g,
                                                 const float* __restrict__ b,
                                                 u16* __restrict__ outp) {
    int tok = blockIdx.x;
    int t = threadIdx.x;
    const float4* row = (const float4*)(in + (size_t)tok * 1024);
    float4 v = row[t];
    float s = v.x + v.y + v.z + v.w;
    float sq = v.x * v.x + v.y * v.y + v.z * v.z + v.w * v.w;
#pragma unroll
    for (int off = 32; off >= 1; off >>= 1) {
        s += __shfl_xor(s, off);
        sq += __shfl_xor(sq, off);
    }
    __shared__ float rs[4], rq[4];
    int lane = t & 63, w = t >> 6;
    if (lane == 0) { rs[w] = s; rq[w] = sq; }
    __syncthreads();
    s = rs[0] + rs[1] + rs[2] + rs[3];
    sq = rq[0] + rq[1] + rq[2] + rq[3];
    float mean = s * (1.0f / 1024.0f);
    float var = sq * (1.0f / 1024.0f) - mean * mean;
    float rstd = rsqrtf(var + 1e-5f);
    float4 gg = ((const float4*)g)[t];
    float4 bb = ((const float4*)b)[t];
    u16* o = outp + (size_t)tok * 1024 + t * 4;
    o[0] = f2bf((v.x - mean) * rstd * gg.x + bb.x);
    o[1] = f2bf((v.y - mean) * rstd * gg.y + bb.y);
    o[2] = f2bf((v.z - mean) * rstd * gg.z + bb.z);
    o[3] = f2bf((v.w - mean) * rstd * gg.w + bb.w);
}

// ---------------- Weight transpose fp32 (K x N) -> bf16 (N x K) ----------------
__global__ __launch_bounds__(256) void transpose_w(const float* __restrict__ W,
                                                   u16* __restrict__ WT, int K, int N) {
    __shared__ float tile[32][33];
    int n0 = blockIdx.x * 32, k0 = blockIdx.y * 32;
    int tx = threadIdx.x & 31, ty = threadIdx.x >> 5;  // ty 0..7
#pragma unroll
    for (int i = 0; i < 4; i++) {
        int kk = ty + i * 8;
        tile[kk][tx] = W[(size_t)(k0 + kk) * N + n0 + tx];
    }
    __syncthreads();
#pragma unroll
    for (int i = 0; i < 4; i++) {
        int nn = ty + i * 8;
        WT[(size_t)(n0 + nn) * K + k0 + tx] = f2bf(tile[tx][nn]);
    }
}

// ---------------- fp32 -> bf16 elementwise ----------------
__global__ void convert_bf(const float* __restrict__ in, u16* __restrict__ outp, int n) {
    int i = blockIdx.x * blockDim.x + threadIdx.x;
    if (i < n) outp[i] = f2bf(in[i]);
}

// ---------------- K/V pre-tiler for attention ----------------
__global__ __launch_bounds__(256) void prep_kv(const u16* __restrict__ src,
                                               u32* __restrict__ kdst, u32* __restrict__ vdst,
                                               long bstride, int rstride, int koff, int voff) {
    int t = blockIdx.x, bh = blockIdx.y;
    int b = bh >> 4, h = bh & 15;
    int tid = threadIdx.x;
    const u16* kS = src + (size_t)b * bstride + (size_t)(t * 64) * rstride + koff + h * 64;
    const u16* vS = src + (size_t)b * bstride + (size_t)(t * 64) * rstride + voff + h * 64;
    u32* kD = kdst + ((size_t)bh * gridDim.x + t) * 2048;
    u32* vD = vdst + ((size_t)bh * gridDim.x + t) * 2048;
#pragma unroll
    for (int c = 0; c < 2; c++) {
        int idx = tid + c * 256;
        int row = idx >> 3, blk = idx & 7;
        uint4 q = *(const uint4*)&kS[(size_t)row * rstride + blk * 8];
        *(uint4*)&kD[row * 32 + ((blk ^ (row & 7)) << 2)] = q;
    }
#pragma unroll
    for (int c = 0; c < 2; c++) {
        int idx = tid + c * 256;
        int drow = idx >> 3, kblk = idx & 7;
        u32 vv[4];
#pragma unroll
        for (int e = 0; e < 4; e++) {
            int j0 = kblk * 8 + 2 * e, j1 = j0 + 1;
            int kv0 = 16 * (j0 & 3) + (j0 >> 2);
            int kv1 = 16 * (j1 & 3) + (j1 >> 2);
            vv[e] = (u32)vS[(size_t)kv0 * rstride + drow] |
                    ((u32)vS[(size_t)kv1 * rstride + drow] << 16);
        }
        *(uint4*)&vD[drow * 32 + ((kblk ^ (drow & 7)) << 2)] = *(uint4*)vv;
    }
}

// ---------------- 256x256 8-wave BK=64 GEMM (T2+T3+T4+T5): C = A * B^T --------
// 512 thr (2Mx4N waves, 128x64 out each), LDS [2buf][4 halves][16KB] = 128KB.
// XOR-swizzled halves (pre-swizzled global source + swizzled ds_read: rule 21).
// 4 phases/K-tile: {stage 1 half-tile || ds_read subtile || 16 MFMA}; vmcnt(2)
// mid-loop (never 0); 2 barriers/K-tile. Requires M%256==0, N%256==0, K%64==0.
// MODE 0: out bf16 = acc + bias ; MODE 1: out bf16 = gelu(acc + bias)
template <int MODE>
__global__ __launch_bounds__(512, 2) void gemm256(const u16* A, const u16* BT,
                                                  const float* __restrict__ bias,
                                                  void* outv, int M, int N, int K) {
    __shared__ __align__(16) u16 lds[2][4][8192];
    int gx = gridDim.x, gy = gridDim.y;
    int id = blockIdx.y * gx + blockIdx.x;
    int id2 = xcd_swz(id, gx * gy);
    int bx = id2 / gy, by = id2 % gy;  // column-major: XCD chunk shares B-panels
    int rowBase = by * 256, colBase = bx * 256;
    int tid = threadIdx.x, lane = tid & 63, w = tid >> 6;
    int wm = w >> 2, wn = w & 3, bh = wn >> 1;
    int r = lane & 15, g = lane >> 4, rb = r & 7;

    // staging: thread covers (row=tid/8 +64j, 16B-blk=tid&7) of a 128x64 half;
    // source column pre-swizzled so linear gload dest + swizzled read match.
    int srow = tid >> 3;
    int swblk = (tid & 7) ^ (srow & 7);
    const u16* aS0 = A + (size_t)(rowBase + srow) * K + swblk * 8;
    const u16* aS1 = A + (size_t)(rowBase + 128 + srow) * K + swblk * 8;
    const u16* bS0 = BT + (size_t)(colBase + srow) * K + swblk * 8;
    const u16* bS1 = BT + (size_t)(colBase + 128 + srow) * K + swblk * 8;
    size_t j64 = (size_t)64 * K;

    auto stageH = [&](int bufi, int h, const u16* src, int kt) {
        const u16* s = src + kt * 64;
        u16* d = &lds[bufi][h][tid * 8];
        gload_lds16(s, d);
        gload_lds16(s + j64, d + 4096);
    };

    f32x4 acc[8][4] = {};
    int NK = K >> 6;
    stageH(0, 0, aS0, 0); stageH(0, 1, aS1, 0);
    stageH(0, 2, bS0, 0); stageH(0, 3, bS1, 0);   // 8 loads in flight

    for (int kt = 0; kt < NK; kt++) {
        int cur = kt & 1, nxt = cur ^ 1;
        bool hasNext = (kt + 1 < NK);
        const u16* Ah = &lds[cur][wm][0];
        const u16* Bh = &lds[cur][2 + bh][0];
        int bro = (wn & 1) * 64;

        // ---- phase 0: stage A-half0(next) ; read aL(mi0-3), b(ni0-1) ; MFMA Q00
        if (hasNext) {
            stageH(nxt, 0, aS0, kt + 1);
            asm volatile("s_waitcnt vmcnt(2)" ::: "memory");  // tile-kt loads done
        } else {
            asm volatile("s_waitcnt vmcnt(0)" ::: "memory");
        }
        __builtin_amdgcn_s_barrier();

        bf16x8 aL[4][2], bb[4][2];
#pragma unroll
        for (int mi = 0; mi < 4; mi++)
#pragma unroll
            for (int kk = 0; kk < 2; kk++)
                aL[mi][kk] = *(const bf16x8*)&Ah[(mi * 16 + r) * 64 + ((kk * 4 + g) ^ rb) * 8];
#pragma unroll
        for (int ni = 0; ni < 2; ni++)
#pragma unroll
            for (int kk = 0; kk < 2; kk++)
                bb[ni][kk] = *(const bf16x8*)&Bh[(bro + ni * 16 + r) * 64 + ((kk * 4 + g) ^ rb) * 8];
        __builtin_amdgcn_s_setprio(1);
#pragma unroll
        for (int mi = 0; mi < 4; mi++)
#pragma unroll
            for (int ni = 0; ni < 2; ni++)
#pragma unroll
                for (int kk = 0; kk < 2; kk++)
                    acc[mi][ni] = __builtin_amdgcn_mfma_f32_16x16x32_bf16(aL[mi][kk], bb[ni][kk], acc[mi][ni], 0, 0, 0);
        __builtin_amdgcn_s_setprio(0);

        // ---- phase 1: stage A-half1(next) ; read b(ni2-3) ; MFMA Q01
        if (hasNext) stageH(nxt, 1, aS1, kt + 1);
#pragma unroll
        for (int ni = 2; ni < 4; ni++)
#pragma unroll
            for (int kk = 0; kk < 2; kk++)
                bb[ni][kk] = *(const bf16x8*)&Bh[(bro + ni * 16 + r) * 64 + ((kk * 4 + g) ^ rb) * 8];
        __builtin_amdgcn_s_setprio(1);
#pragma unroll
        for (int mi = 0; mi < 4; mi++)
#pragma unroll
            for (int ni = 2; ni < 4; ni++)
#pragma unroll
                for (int kk = 0; kk < 2; kk++)
                    acc[mi][ni] = __builtin_amdgcn_mfma_f32_16x16x32_bf16(aL[mi][kk], bb[ni][kk], acc[mi][ni], 0, 0, 0);
        __builtin_amdgcn_s_setprio(0);

        // ---- phase 2: stage B-half0(next) ; read aH(mi4-7) ; MFMA Q11
        if (hasNext) stageH(nxt, 2, bS0, kt + 1);
        bf16x8 aH[4][2];
#pragma unroll
        for (int mi = 0; mi < 4; mi++)
#pragma unroll
            for (int kk = 0; kk < 2; kk++)
                aH[mi][kk] = *(const bf16x8*)&Ah[((mi + 4) * 16 + r) * 64 + ((kk * 4 + g) ^ rb) * 8];
        __builtin_amdgcn_s_setprio(1);
#pragma unroll
        for (int mi = 0; mi < 4; mi++)
#pragma unroll
            for (int ni = 2; ni < 4; ni++)
#pragma unroll
                for (int kk = 0; kk < 2; kk++)
                    acc[mi + 4][ni] = __builtin_amdgcn_mfma_f32_16x16x32_bf16(aH[mi][kk], bb[ni][kk], acc[mi + 4][ni], 0, 0, 0);
        __builtin_amdgcn_s_setprio(0);

        // ---- phase 3: stage B-half1(next) ; MFMA Q10 (all frags in regs)
        if (hasNext) stageH(nxt, 3, bS1, kt + 1);
        __builtin_amdgcn_s_setprio(1);
#pragma unroll
        for (int mi = 0; mi < 4; mi++)
#pragma unroll
            for (int ni = 0; ni < 2; ni++)
#pragma unroll
                for (int kk = 0; kk < 2; kk++)
                    acc[mi + 4][ni] = __builtin_amdgcn_mfma_f32_16x16x32_bf16(aH[mi][kk], bb[ni][kk], acc[mi + 4][ni], 0, 0, 0);
        __builtin_amdgcn_s_setprio(0);
        __builtin_amdgcn_s_barrier();  // WAR: cur fully read before next iter re-stages it
    }

#pragma unroll
    for (int mi = 0; mi < 8; mi++) {
#pragma unroll
        for (int ni = 0; ni < 4; ni++) {
#pragma unroll
            for (int rr = 0; rr < 4; rr++) {
                int grow = rowBase + wm * 128 + mi * 16 + g * 4 + rr;
                int gcol = colBase + wn * 64 + ni * 16 + r;
                float v = acc[mi][ni][rr] + bias[gcol];
                if constexpr (MODE == 1) {
                    v = 0.5f * v * (1.0f + erff(v * 0.70710678118f));
                }
                ((u16*)outv)[(size_t)grow * N + gcol] = f2bf(v);
            }
        }
    }
}

// ---------------- Generic bf16 MFMA GEMM (128-col tiles, depth-3 pipeline) ----
// Used for the N=1024 GEMMs (out-proj, fc2) and the tiny mem GEMM.
// MODE 0: out bf16 = acc + bias ; MODE 1: gelu ; MODE 2: f32 acc + bias + res
template <int MODE, int BM>
__global__ __launch_bounds__(256) void gemm_bf16(const u16* A, const u16* BT,
                                                 const float* __restrict__ bias,
                                                 const float* res, void* outv,
                                                 int M, int N, int K) {
    __shared__ __align__(16) u16 As[3][BM * 32];
    __shared__ __align__(16) u16 Bs[3][128 * 32];
    constexpr int MI = BM / 32;
    int gx = gridDim.x, gy = gridDim.y;
    int id = blockIdx.y * gx + blockIdx.x;
    int id2 = xcd_swz(id, gx * gy);
    int bx = id2 / gy, by = id2 % gy;
    int rowBase = by * BM, colBase = bx * 128;
    int t = threadIdx.x, lane = t & 63, w = t >> 6;
    int wr = w >> 1, wc = w & 1, r = lane & 15, g = lane >> 4;

    int lrow = lane >> 2;
    int scol = (lane & 3) * 8;
    const u16* b0 = BT + (size_t)(colBase + (w * 2 + 0) * 16 + lrow) * K + scol;
    const u16* b1 = BT + (size_t)(colBase + (w * 2 + 1) * 16 + lrow) * K + scol;
    int lB0 = (w * 2 + 0) * 512;
    int lB1 = (w * 2 + 1) * 512;
    const u16* a0;
    const u16* a1 = nullptr;
    int lA0, lA1 = 0;
    if constexpr (BM == 128) {
        a0 = A + (size_t)(rowBase + (w * 2 + 0) * 16 + lrow) * K + scol;
        a1 = A + (size_t)(rowBase + (w * 2 + 1) * 16 + lrow) * K + scol;
        lA0 = (w * 2 + 0) * 512;
        lA1 = (w * 2 + 1) * 512;
    } else {
        a0 = A + (size_t)(rowBase + w * 16 + lrow) * K + scol;
        lA0 = w * 512;
    }

    auto stage = [&](int k0, u16* Ab, u16* Bb) {
        gload_lds16(a0 + k0, Ab + lA0);
        if constexpr (BM == 128) gload_lds16(a1 + k0, Ab + lA1);
        gload_lds16(b0 + k0, Bb + lB0);
        gload_lds16(b1 + k0, Bb + lB1);
    };

    u16 *pA0 = &As[0][0], *pA1 = &As[1][0], *pA2 = &As[2][0];
    u16 *pB0 = &Bs[0][0], *pB1 = &Bs[1][0], *pB2 = &Bs[2][0];

    f32x4 acc[MI][4] = {};
    int nk = K >> 5;
    stage(0, pA0, pB0);
    stage(32, pA1, pB1);
    for (int kt = 0; kt < nk; kt++) {
        if (kt + 2 < nk) {
            stage((kt + 2) << 5, pA2, pB2);
            if constexpr (BM == 128) asm volatile("s_waitcnt vmcnt(8)" ::: "memory");
            else                     asm volatile("s_waitcnt vmcnt(6)" ::: "memory");
        } else if (kt + 1 < nk) {
            if constexpr (BM == 128) asm volatile("s_waitcnt vmcnt(4)" ::: "memory");
            else                     asm volatile("s_waitcnt vmcnt(3)" ::: "memory");
        } else {
            asm volatile("s_waitcnt vmcnt(0)" ::: "memory");
        }
        __builtin_amdgcn_s_barrier();
        bf16x8 af[MI], bfr[4];
#pragma unroll
        for (int mi = 0; mi < MI; mi++)
            af[mi] = *(const bf16x8*)&pA0[(wr * (BM / 2) + mi * 16 + r) * 32 + g * 8];
#pragma unroll
        for (int ni = 0; ni < 4; ni++)
            bfr[ni] = *(const bf16x8*)&pB0[(wc * 64 + ni * 16 + r) * 32 + g * 8];
        __builtin_amdgcn_s_setprio(1);
#pragma unroll
        for (int mi = 0; mi < MI; mi++)
#pragma unroll
            for (int ni = 0; ni < 4; ni++)
                acc[mi][ni] = __builtin_amdgcn_mfma_f32_16x16x32_bf16(af[mi], bfr[ni], acc[mi][ni], 0, 0, 0);
        __builtin_amdgcn_s_setprio(0);
        __builtin_amdgcn_s_barrier();
        u16* tA = pA0; pA0 = pA1; pA1 = pA2; pA2 = tA;
        u16* tB = pB0; pB0 = pB1; pB1 = pB2; pB2 = tB;
    }

#pragma unroll
    for (int mi = 0; mi < MI; mi++) {
#pragma unroll
        for (int ni = 0; ni < 4; ni++) {
#pragma unroll
            for (int rr = 0; rr < 4; rr++) {
                int grow = rowBase + wr * (BM / 2) + mi * 16 + g * 4 + rr;
                int gcol = colBase + wc * 64 + ni * 16 + r;
                if (grow < M) {
                    float v = acc[mi][ni][rr] + bias[gcol];
                    if constexpr (MODE == 1) {
                        v = 0.5f * v * (1.0f + erff(v * 0.70710678118f));
                    }
                    if constexpr (MODE == 2) {
                        ((float*)outv)[(size_t)grow * N + gcol] = v + res[(size_t)grow * N + gcol];
                    } else {
                        ((u16*)outv)[(size_t)grow * N + gcol] = f2bf(v);
                    }
                }
            }
        }
    }
}

// ---------------- Flash attention + compressive memory read ----------------
__global__ __launch_bounds__(256) void attn_kernel(const u16* __restrict__ qkv,
                                                   const u32* __restrict__ ktiled,
                                                   const u32* __restrict__ vttiled,
                                                   const u32* __restrict__ memK,
                                                   const u32* __restrict__ memVT,
                                                   u16* __restrict__ outp) {
    __shared__ __align__(16) u32 KB[2][2048];   // [64 rows][32 u32], blk^=(row&7)
    __shared__ __align__(16) u32 VB[2][2048];
    __shared__ __align__(16) u32 P32[64][32];   // blk^=(row&7)
    const int T = 2048, C3 = 3072;
    int id = blockIdx.y * 32 + blockIdx.x;
    int id2 = xcd_swz(id, 1024);
    int bh = id2 >> 5, qt = id2 & 31;
    int b = bh >> 4, h = bh & 15;
    int t0 = qt * 64;
    int tid = threadIdx.x, lane = tid & 63, w = tid >> 6, r = lane & 15, g = lane >> 4;
    int swz = r & 7;
    size_t qkvb = (size_t)b * T * C3;

    // Q fragments, pre-scaled by 1/sqrt(D) * log2(e) (S in log2 domain)
    const u16* qrow = qkv + qkvb + (size_t)(t0 + w * 16 + r) * C3 + h * 64;
    bf16x8 aq0 = *(const bf16x8*)(qrow + g * 8);
    bf16x8 aq1 = *(const bf16x8*)(qrow + 32 + g * 8);
#pragma unroll
    for (int i = 0; i < 8; i++) {
        float f0 = __uint_as_float(((u32)(u16)aq0[i]) << 16) * 0.18033688f;
        float f1 = __uint_as_float(((u32)(u16)aq1[i]) << 16) * 0.18033688f;
        aq0[i] = (short)f2bf(f0);
        aq1[i] = (short)f2bf(f1);
    }

    f32x4 O[4] = {};
    float m_[4] = {-1e30f, -1e30f, -1e30f, -1e30f};
    float lv[4] = {0.f, 0.f, 0.f, 0.f};

    auto stage = [&](int t, int buf) {
        const u32 *kb, *vb;
        if (t < 32) {
            kb = ktiled + ((size_t)bh * 32 + t) * 2048;
            vb = vttiled + ((size_t)bh * 32 + t) * 2048;
        } else {
            kb = memK + (size_t)h * 2048;
            vb = memVT + (size_t)h * 2048;
        }
        gload_lds16((const u16*)(kb + tid * 4), (u16*)&KB[buf][tid * 4]);
        gload_lds16((const u16*)(kb + 1024 + tid * 4), (u16*)&KB[buf][1024 + tid * 4]);
        gload_lds16((const u16*)(vb + tid * 4), (u16*)&VB[buf][tid * 4]);
        gload_lds16((const u16*)(vb + 1024 + tid * 4), (u16*)&VB[buf][1024 + tid * 4]);
    };

    auto compute = [&](int buf) {
        f32x4 sv[4];
#pragma unroll
        for (int n = 0; n < 4; n++) {
            int row = n * 16 + r;
            bf16x8 bk0 = *(const bf16x8*)&KB[buf][row * 32 + ((g ^ swz) << 2)];
            bf16x8 bk1 = *(const bf16x8*)&KB[buf][row * 32 + (((4 + g) ^ swz) << 2)];
            f32x4 z = {0.f, 0.f, 0.f, 0.f};
            z = __builtin_amdgcn_mfma_f32_16x16x32_bf16(aq0, bk0, z, 0, 0, 0);
            z = __builtin_amdgcn_mfma_f32_16x16x32_bf16(aq1, bk1, z, 0, 0, 0);
            sv[n] = z;
        }
        // defer-max: lane-local check, full reduce+rescale only when violated
        float mxl[4];
#pragma unroll
        for (int rr = 0; rr < 4; rr++)
            mxl[rr] = fmaxf(fmaxf(sv[0][rr], sv[1][rr]), fmaxf(sv[2][rr], sv[3][rr]));
        float dmax = fmaxf(fmaxf(mxl[0] - m_[0], mxl[1] - m_[1]),
                           fmaxf(mxl[2] - m_[2], mxl[3] - m_[3]));
        if (!__all(dmax <= 8.0f)) {
#pragma unroll
            for (int rr = 0; rr < 4; rr++) {
                float mxr = mxl[rr];
#pragma unroll
                for (int off = 8; off >= 1; off >>= 1) mxr = fmaxf(mxr, __shfl_xor(mxr, off));
                float mn = fmaxf(m_[rr], mxr);
                float alpha = exp2f(m_[rr] - mn);
                m_[rr] = mn;
                lv[rr] *= alpha;
#pragma unroll
                for (int n = 0; n < 4; n++) O[n][rr] *= alpha;
            }
        }
        // P = exp2(S - m), truncation-packed along k'
#pragma unroll
        for (int rr = 0; rr < 4; rr++) {
            int q = w * 16 + g * 4 + rr;
            float p0 = exp2f(sv[0][rr] - m_[rr]);
            float p1 = exp2f(sv[1][rr] - m_[rr]);
            float p2 = exp2f(sv[2][rr] - m_[rr]);
            float p3 = exp2f(sv[3][rr] - m_[rr]);
            lv[rr] += (p0 + p1) + (p2 + p3);
            uint2 pw;
            pw.x = __builtin_amdgcn_perm(__float_as_uint(p1), __float_as_uint(p0), 0x07060302u);
            pw.y = __builtin_amdgcn_perm(__float_as_uint(p3), __float_as_uint(p2), 0x07060302u);
            *(uint2*)&P32[q][4 * ((r >> 1) ^ (q & 7)) + 2 * (r & 1)] = pw;
        }
        // O += P V  (same-wave LDS dep; rows w*16..w*16+15 only)
        bf16x8 ap0 = *(const bf16x8*)&P32[w * 16 + r][(g ^ swz) << 2];
        bf16x8 ap1 = *(const bf16x8*)&P32[w * 16 + r][((4 + g) ^ swz) << 2];
#pragma unroll
        for (int n = 0; n < 4; n++) {
            int row = n * 16 + r;
            bf16x8 bv0 = *(const bf16x8*)&VB[buf][row * 32 + ((g ^ swz) << 2)];
            bf16x8 bv1 = *(const bf16x8*)&VB[buf][row * 32 + (((4 + g) ^ swz) << 2)];
            O[n] = __builtin_amdgcn_mfma_f32_16x16x32_bf16(ap0, bv0, O[n], 0, 0, 0);
            O[n] = __builtin_amdgcn_mfma_f32_16x16x32_bf16(ap1, bv1, O[n], 0, 0, 0);
        }
    };

    float outLocal[4][4];
    stage(0, 0);
    __syncthreads();
    for (int tt = 0; tt <= 32; tt++) {
        if (tt < 32) stage(tt + 1, (tt + 1) & 1);
        if (tt == 32) {
            // finalize local attention before the mem tile
#pragma unroll
            for (int rr = 0; rr < 4; rr++) {
                float ls = lv[rr];
#pragma unroll
                for (int off = 8; off >= 1; off >>= 1) ls += __shfl_xor(ls, off);
                float inv = 1.0f / ls;
#pragma unroll
                for (int n = 0; n < 4; n++) outLocal[n][rr] = O[n][rr] * inv;
                m_[rr] = -1e30f;
                lv[rr] = 0.f;
            }
#pragma unroll
            for (int n = 0; n < 4; n++) { f32x4 z = {0.f, 0.f, 0.f, 0.f}; O[n] = z; }
        }
        compute(tt & 1);
        __syncthreads();
    }
#pragma unroll
    for (int rr = 0; rr < 4; rr++) {
        float ls = lv[rr];
#pragma unroll
        for (int off = 8; off >= 1; off >>= 1) ls += __shfl_xor(ls, off);
        float inv = 1.0f / ls;
        int row = t0 + w * 16 + g * 4 + rr;
#pragma unroll
        for (int n = 0; n < 4; n++) {
            float v2 = outLocal[n][rr] + O[n][rr] * inv;
            outp[((size_t)(b * T + row)) * 1024 + h * 64 + n * 16 + r] = f2bf(v2);
        }
    }
}

extern "C" void kernel_launch(void* const* d_in, const int* in_sizes, int n_in,
                              void* d_out, int out_size, void* d_ws, size_t ws_size,
                              hipStream_t stream) {
    const float* x      = (const float*)d_in[0];
    const float* memory = (const float*)d_in[1];
    const float* ln1_g  = (const float*)d_in[2];
    const float* ln1_b  = (const float*)d_in[3];
    const float* w_qkv  = (const float*)d_in[4];
    const float* b_qkv  = (const float*)d_in[5];
    const float* w_out  = (const float*)d_in[6];
    const float* b_out  = (const float*)d_in[7];
    const float* w_mem  = (const float*)d_in[8];
    const float* b_mem  = (const float*)d_in[9];
    const float* ln2_g  = (const float*)d_in[10];
    const float* ln2_b  = (const float*)d_in[11];
    const float* w_fc1  = (const float*)d_in[12];
    const float* b_fc1  = (const float*)d_in[13];
    const float* w_fc2  = (const float*)d_in[14];
    const float* b_fc2  = (const float*)d_in[15];
    float* out = (float*)d_out;

    char* ws = (char*)d_ws;
    size_t off = 0;
    auto alloc = [&](size_t bytes) { size_t o = off; off += (bytes + 255) & ~(size_t)255; return o; };
    u16* h_bf    = (u16*)(ws + alloc((size_t)4096 * 1024 * 2));  // reused for h2
    u16* qkv_bf  = (u16*)(ws + alloc((size_t)4096 * 3072 * 2));
    u16* attn_bf = (u16*)(ws + alloc((size_t)4096 * 1024 * 2));
    u16* g1_bf   = (u16*)(ws + alloc((size_t)4096 * 4096 * 2));
    u16* mem_bf  = (u16*)(ws + alloc((size_t)64 * 1024 * 2));
    u16* memA_bf = (u16*)(ws + alloc((size_t)64 * 1024 * 2));
    u16* wqkvT   = (u16*)(ws + alloc((size_t)3072 * 1024 * 2));
    u16* woutT   = (u16*)(ws + alloc((size_t)1024 * 1024 * 2));
    u16* wmemT   = (u16*)(ws + alloc((size_t)1024 * 1024 * 2));
    u16* wfc1T   = (u16*)(ws + alloc((size_t)4096 * 1024 * 2));
    u16* wfc2T   = (u16*)(ws + alloc((size_t)1024 * 4096 * 2));

    // K/V pre-tiled buffers alias the g1_bf region (lifetimes disjoint: prep+attn
    // finish before fc1 writes g1_bf).
    u32* ktiled  = (u32*)g1_bf;                    // 32bh x 32t x 2048 u32 = 8 MB
    u32* vttiled = ktiled + (size_t)1024 * 2048;   // 8 MB
    u32* memK    = vttiled + (size_t)1024 * 2048;  // 16h x 2048 u32 = 128 KB
    u32* memVT   = memK + (size_t)16 * 2048;       // 128 KB

    // weights -> bf16 transposed (N x K)
    transpose_w<<<dim3(3072 / 32, 1024 / 32), 256, 0, stream>>>(w_qkv, wqkvT, 1024, 3072);
    transpose_w<<<dim3(1024 / 32, 1024 / 32), 256, 0, stream>>>(w_out, woutT, 1024, 1024);
    transpose_w<<<dim3(1024 / 32, 1024 / 32), 256, 0, stream>>>(w_mem, wmemT, 1024, 1024);
    transpose_w<<<dim3(4096 / 32, 1024 / 32), 256, 0, stream>>>(w_fc1, wfc1T, 1024, 4096);
    transpose_w<<<dim3(1024 / 32, 4096 / 32), 256, 0, stream>>>(w_fc2, wfc2T, 4096, 1024);
    convert_bf<<<dim3(256), 256, 0, stream>>>(memory, memA_bf, 64 * 1024);

    // LN1: x -> h (bf16)
    ln_kernel<<<dim3(4096), 256, 0, stream>>>(x, ln1_g, ln1_b, h_bf);

    // qkv = h @ w_qkv + b_qkv   (bf16 out) — 256² 8-phase kernel, 192 blocks
    gemm256<0><<<dim3(12, 16), 512, 0, stream>>>(h_bf, wqkvT, b_qkv, qkv_bf, 4096, 3072, 1024);

    // mem = memory @ w_mem + b_mem  (bf16 out, 64 x 1024)
    gemm_bf16<0, 64><<<dim3(8, 1), 256, 0, stream>>>(memA_bf, wmemT, b_mem, nullptr, mem_bf, 64, 1024, 1024);

    // pre-tile K and V^T (local KV from qkv; mem KV from mem_bf)
    prep_kv<<<dim3(32, 32), 256, 0, stream>>>(qkv_bf, ktiled, vttiled,
                                              (long)2048 * 3072, 3072, 1024, 2048);
    prep_kv<<<dim3(1, 16), 256, 0, stream>>>(mem_bf, memK, memVT, 0, 1024, 0, 0);

    // attention (local + memory) -> attn_bf
    attn_kernel<<<dim3(32, 32), 256, 0, stream>>>(qkv_bf, ktiled, vttiled, memK, memVT, attn_bf);

    // x1 = x + attn @ w_out + b_out   (fp32, lives in d_out)
    gemm_bf16<2, 64><<<dim3(8, 64), 256, 0, stream>>>(attn_bf, woutT, b_out, x, out, 4096, 1024, 1024);

    // LN2: x1 -> h2 (bf16, reuse h_bf)
    ln_kernel<<<dim3(4096), 256, 0, stream>>>(out, ln2_g, ln2_b, h_bf);

    // g1 = gelu(h2 @ w_fc1 + b_fc1)  (bf16) — 256² 8-phase kernel, 256 blocks
    gemm256<1><<<dim3(16, 16), 512, 0, stream>>>(h_bf, wfc1T, b_fc1, g1_bf, 4096, 4096, 1024);

    // out = x1 + g1 @ w_fc2 + b_fc2  (fp32, in-place over x1)
    gemm_bf16<2, 64><<<dim3(8, 64), 256, 0, stream>>>(g1_bf, wfc2T, b_fc2, out, out, 4096, 1024, 4096);

    (void)in_sizes; (void)n_in; (void)out_size; (void)ws_size;
}